// Round 9
// baseline (462.956 us; speedup 1.0000x reference)
//
#include <hip/hip_runtime.h>
#include <hip/hip_bf16.h>
#include <cstdint>
#include <cstddef>

#define N_NODES 50000
#define N_EDGES 800000
#define NR      50048    // N_NODES rounded up (hFT row stride, floats)
#define NBKT    196      // ceil(50000/256) buckets of 256 rows
#define BSH     8        // rows-per-bucket shift
#define BCHUNK  2048     // edges per bin_k block
#define CAP     6144     // max edges per bucket (mean 4082)

typedef __attribute__((ext_vector_type(8))) short short8;
typedef __attribute__((ext_vector_type(4))) float floatx4;
typedef __attribute__((ext_vector_type(4))) unsigned int uintx4;

__device__ inline float bf2f(unsigned short u) {
    union { unsigned int i; float f; } v; v.i = ((unsigned int)u) << 16; return v.f;
}
__device__ inline unsigned short f2bf(float f) {
    union { float f; unsigned int i; } v; v.f = f;
    unsigned int u = v.i;
    return (unsigned short)((u + 0x7FFFu + ((u >> 16) & 1u)) >> 16);
}
// packed RNE f32x2 -> bf16x2 (v_cvt_pk_bf16_f32 on gfx950)
__device__ inline unsigned int f2bf_pk(float a, float b) {
    __hip_bfloat162 h2 = __float22bfloat162_rn(make_float2(a, b));
    return *reinterpret_cast<unsigned int*>(&h2);
}
// unpack 2 bf16 (packed in a uint) to 2 floats
__device__ inline float2 bf2f2(unsigned int u) {
    union { unsigned int i; float f; } lo, hi;
    lo.i = u << 16;
    hi.i = u & 0xFFFF0000u;
    return make_float2(lo.f, hi.f);
}
// silu via v_rcp_f32 (1 ulp) instead of IEEE divide
__device__ inline float silu_f(float x) {
    float e = __expf(-x);
    return x * __builtin_amdgcn_rcpf(1.0f + e);
}

__device__ inline int block_excl_scan_256(int v, int* buf) {
    int tid = threadIdx.x;
    buf[tid] = v;
    __syncthreads();
    #pragma unroll
    for (int off = 1; off < 256; off <<= 1) {
        int t = (tid >= off) ? buf[tid - off] : 0;
        __syncthreads();
        buf[tid] += t;
        __syncthreads();
    }
    return buf[tid] - v;
}

// ---------------------------------------------------------------------------
// Pack kernel: fp32->bf16 conversions + weight rearrangement into MFMA
// B-fragment order: Bp[(kb*NOUT + n)*8 + i] = B[(kb*8+i)*NOUT + n]
// ---------------------------------------------------------------------------
__device__ inline void pack_std(const float* __restrict__ src,
                                unsigned short* __restrict__ dst,
                                int NOUT, long j) {
    int i = (int)(j & 7);
    long rest = j >> 3;
    int n = (int)(rest % NOUT);
    int kb = (int)(rest / NOUT);
    dst[j] = f2bf(src[(long)(kb * 8 + i) * NOUT + n]);
}

#define NH0   (N_NODES * 64L)
#define SW_IN 8192L
#define SW_OUT 8192L
#define SW1   16384L
#define SE2   4096L
#define SN1   24576L
#define SN2   16384L
#define SB    128L
#define PERL  (SW1 + SE2 + SN1 + SN2 + SB)
#define PACK_TOTAL (NH0 + SW_IN + SW_OUT + 4 * PERL)

__global__ __launch_bounds__(256) void pack_kernel(
    const float* __restrict__ h0, const float* __restrict__ W_in,
    const float* __restrict__ W_out, const float* __restrict__ eW1,
    const float* __restrict__ eb1, const float* __restrict__ eW2,
    const float* __restrict__ nW1, const float* __restrict__ nW2,
    unsigned short* __restrict__ h0bf, unsigned short* __restrict__ Winp,
    unsigned short* __restrict__ Woutp, unsigned short* __restrict__ W1p,
    unsigned short* __restrict__ eW2p, unsigned short* __restrict__ nW1p,
    unsigned short* __restrict__ nW2p, float* __restrict__ biasP)
{
    long idx = (long)blockIdx.x * 256 + threadIdx.x;
    if (idx >= PACK_TOTAL) return;
    long j = idx;
    if (j < NH0) { h0bf[j] = f2bf(h0[j]); return; }
    j -= NH0;
    if (j < SW_IN) { pack_std(W_in, Winp, 128, j); return; }
    j -= SW_IN;
    if (j < SW_OUT) { pack_std(W_out, Woutp, 64, j); return; }
    j -= SW_OUT;
    int l = (int)(j / PERL);
    long r = j % PERL;
    if (r < SW1) {
        int i = (int)(r & 7);
        int n = (int)((r >> 3) & 127);
        int kb = (int)(r >> 10);
        int k = kb * 8 + i;
        const float* w = eW1 + (long)l * 256 * 64;
        float v = (n < 64) ? w[(long)k * 64 + n] : w[(long)(128 + k) * 64 + (n - 64)];
        W1p[(long)l * SW1 + r] = f2bf(v);
        return;
    }
    r -= SW1;
    if (r < SE2) { pack_std(eW2 + (long)l * 4096, eW2p + (long)l * SE2, 64, r); return; }
    r -= SE2;
    if (r < SN1) { pack_std(nW1 + (long)l * 24576, nW1p + (long)l * SN1, 128, r); return; }
    r -= SN1;
    if (r < SN2) { pack_std(nW2 + (long)l * 16384, nW2p + (long)l * SN2, 128, r); return; }
    r -= SN2;
    biasP[(long)l * 128 + r] = (r < 64) ? eb1[(long)l * 64 + r] : 0.0f;
}

// ---------------------------------------------------------------------------
// Edge-sort pipeline
// ---------------------------------------------------------------------------
__global__ __launch_bounds__(256) void hist_k(const int* __restrict__ erow,
                                              int* __restrict__ countB, int E) {
    __shared__ int c[NBKT];
    for (int i = threadIdx.x; i < NBKT; i += 256) c[i] = 0;
    __syncthreads();
    int j = blockIdx.x * BCHUNK + threadIdx.x;
    #pragma unroll
    for (int i = 0; i < BCHUNK / 256; i++, j += 256)
        if (j < E) atomicAdd(&c[erow[j] >> BSH], 1);
    __syncthreads();
    for (int i = threadIdx.x; i < NBKT; i += 256)
        if (c[i]) atomicAdd(&countB[i], c[i]);
}

__global__ __launch_bounds__(256) void bucket_scan_k(const int* __restrict__ countB,
                                                     int* __restrict__ bucketBase,
                                                     int* __restrict__ bucketCursor) {
    __shared__ int buf[256];
    int tid = threadIdx.x;
    int v = (tid < NBKT) ? countB[tid] : 0;
    int excl = block_excl_scan_256(v, buf);
    if (tid < NBKT) {
        bucketBase[tid] = excl;
        bucketCursor[tid] = excl;
    }
    if (tid == NBKT - 1) bucketBase[NBKT] = excl + v;   // = E
}

__global__ __launch_bounds__(256) void bin_k(
    const int* __restrict__ erow, const int* __restrict__ ecol,
    int* __restrict__ bucketCursor, int2* __restrict__ binned, int E)
{
    __shared__ int2 staged[BCHUNK];
    __shared__ int cnt[NBKT];
    __shared__ int binStart[NBKT];
    __shared__ int gbase[NBKT];
    __shared__ int scanbuf[256];
    const int tid = threadIdx.x;
    const int base = blockIdx.x * BCHUNK;
    const int nloc = min(BCHUNK, E - base);

    for (int i = tid; i < NBKT; i += 256) cnt[i] = 0;
    __syncthreads();

    int2 ed[BCHUNK / 256];
    int  bo[BCHUNK / 256];
    #pragma unroll
    for (int i = 0; i < BCHUNK / 256; i++) {
        int jl = i * 256 + tid;
        if (jl < nloc) {
            int j = base + jl;
            int r = erow[j], c = ecol[j];
            ed[i] = make_int2(r, c);
            int b = r >> BSH;
            int off = atomicAdd(&cnt[b], 1);
            bo[i] = (b << 12) | off;
        } else bo[i] = -1;
    }
    __syncthreads();

    int v = (tid < NBKT) ? cnt[tid] : 0;
    int excl = block_excl_scan_256(v, scanbuf);
    if (tid < NBKT) binStart[tid] = excl;
    if (tid < NBKT && v > 0) gbase[tid] = atomicAdd(&bucketCursor[tid], v);
    __syncthreads();

    #pragma unroll
    for (int i = 0; i < BCHUNK / 256; i++) {
        if (bo[i] >= 0)
            staged[binStart[bo[i] >> 12] + (bo[i] & 0xFFF)] = ed[i];
    }
    __syncthreads();

    for (int j = tid; j < nloc; j += 256) {
        int2 e = staged[j];
        int b = e.x >> BSH;
        binned[gbase[b] + (j - binStart[b])] = e;
    }
}

// R9: single LDS buffer; final scatter goes straight to global (bucket
// region is ~32KB -> L2-combined). LDS 98KB -> 52KB.
__global__ __launch_bounds__(256) void sort_k(
    const int2* __restrict__ binned, const int* __restrict__ bucketBase,
    int2* __restrict__ eidx)
{
    __shared__ int2 st[CAP];
    __shared__ int cnt[256];
    __shared__ int cur[256];
    __shared__ int scanbuf[256];
    const int b = blockIdx.x;
    const int tid = threadIdx.x;
    const int s0 = bucketBase[b];
    int n = bucketBase[b + 1] - s0;
    if (n > CAP) n = CAP;

    cnt[tid] = 0;
    __syncthreads();
    for (int j = tid; j < n; j += 256) {
        int2 e = binned[s0 + j];
        st[j] = e;
        atomicAdd(&cnt[e.x & 255], 1);
    }
    __syncthreads();
    int excl = block_excl_scan_256(cnt[tid], scanbuf);
    cur[tid] = excl;
    __syncthreads();
    for (int j = tid; j < n; j += 256) {
        int2 e = st[j];
        int pos = atomicAdd(&cur[e.x & 255], 1);
        eidx[s0 + pos] = e;
    }
}

// ---------------------------------------------------------------------------
// Fused edge + block-segmented aggregate over sorted edges (unchanged R8).
// ---------------------------------------------------------------------------
__global__ __launch_bounds__(256) void edge_fused_k(
    const int2* __restrict__ eidx,
    const unsigned short* __restrict__ P,    // [N,128]: 0..63 top(+b1), 64..127 bot
    const unsigned short* __restrict__ Bp,   // eW2 frag order
    const float* __restrict__ b2, float* __restrict__ agg, int E)
{
    __shared__ float M2s[64 * 68];
    __shared__ int ridS[64];
    __shared__ short segStartS[66];
    __shared__ int nsegS;
    const int tid = threadIdx.x;
    const int wave = tid >> 6;
    const int lane = tid & 63;
    const int lrow = lane & 15;
    const int quad = lane >> 4;
    const int e0 = blockIdx.x * 64;
    const int el = wave * 16 + lrow;
    const int e = e0 + el;

    short8 af0 = {0, 0, 0, 0, 0, 0, 0, 0};
    short8 af1 = af0;
    if (e < E) {
        int2 rc = eidx[e];
        int rr = rc.x, cc = rc.y;
        if (quad == 0) ridS[el] = rr;
        const uintx4* pt = (const uintx4*)(P + (size_t)rr * 128 + quad * 8);
        const uintx4* pb = (const uintx4*)(P + (size_t)cc * 128 + 64 + quad * 8);
        uintx4 t0 = pt[0], t1 = pt[4];
        uintx4 b0 = pb[0], b1 = pb[4];
        const unsigned int* t0u = (const unsigned int*)&t0;
        const unsigned int* t1u = (const unsigned int*)&t1;
        const unsigned int* b0u = (const unsigned int*)&b0;
        const unsigned int* b1u = (const unsigned int*)&b1;
        unsigned int o0[4], o1[4];
        #pragma unroll
        for (int i = 0; i < 4; i++) {
            float2 a0 = bf2f2(t0u[i]), c0 = bf2f2(b0u[i]);
            o0[i] = f2bf_pk(silu_f(a0.x + c0.x), silu_f(a0.y + c0.y));
            float2 a1 = bf2f2(t1u[i]), c1 = bf2f2(b1u[i]);
            o1[i] = f2bf_pk(silu_f(a1.x + c1.x), silu_f(a1.y + c1.y));
        }
        af0 = *(const short8*)o0;
        af1 = *(const short8*)o1;
    } else if (quad == 0) {
        ridS[el] = -1;
    }

    floatx4 acc[4];
    #pragma unroll
    for (int i = 0; i < 4; i++) acc[i] = (floatx4){0, 0, 0, 0};
    #pragma unroll
    for (int nt = 0; nt < 4; nt++) {
        short8 bf0 = *(const short8*)(Bp + (size_t)((0 * 4 + quad) * 64 + nt * 16 + lrow) * 8);
        acc[nt] = __builtin_amdgcn_mfma_f32_16x16x32_bf16(af0, bf0, acc[nt], 0, 0, 0);
        short8 bf1 = *(const short8*)(Bp + (size_t)((1 * 4 + quad) * 64 + nt * 16 + lrow) * 8);
        acc[nt] = __builtin_amdgcn_mfma_f32_16x16x32_bf16(af1, bf1, acc[nt], 0, 0, 0);
    }

    #pragma unroll
    for (int nt = 0; nt < 4; nt++) {
        int n = nt * 16 + lrow;
        float bv = b2[n];
        #pragma unroll
        for (int r = 0; r < 4; r++) {
            int el2 = wave * 16 + quad * 4 + r;
            M2s[el2 * 68 + n] = silu_f(acc[nt][r] + bv);
        }
    }
    __syncthreads();

    if (tid < 64) {
        bool st = (ridS[tid] >= 0) && (tid == 0 || ridS[tid] != ridS[tid - 1]);
        unsigned long long m = __ballot(st);
        if (st) {
            int pos = __popcll(m & ((1ull << tid) - 1));
            segStartS[pos] = (short)tid;
        }
        if (tid == 0) {
            int ns = __popcll(m);
            nsegS = ns;
            int nvalid = E - e0;
            if (nvalid > 64) nvalid = 64;
            segStartS[ns] = (short)nvalid;
        }
    }
    __syncthreads();

    {
        int f = tid & 63;
        int g = tid >> 6;
        int ns = nsegS;
        for (int j = g; j < ns; j += 4) {
            int a = segStartS[j], b = segStartS[j + 1];
            float s = 0.0f;
            for (int el2 = a; el2 < b; el2++) s += M2s[el2 * 68 + f];
            int rv = ridS[a];
            if (j == 0 || j == ns - 1)
                atomicAdd(&agg[(size_t)rv * 64 + f], s);
            else
                agg[(size_t)rv * 64 + f] = s;
        }
    }
}

// ---------------------------------------------------------------------------
// Fused node-side chain, R9: agg A-fragments loaded straight into registers
// (no LDS staging for agg) -> SROW 264, LDS 33792 B; __launch_bounds__(512,8)
// targets VGPR<=64 for 4 blocks (32 waves)/CU.
// LDS col phases: staged h [0,128) -> t [128,256) -> h_new [0,128) ->
// P/out [128,256). Barriers: B1 staging, B2 t, B3 h_new, B4 stores.
// ---------------------------------------------------------------------------
#define SROW 264
template<int FINAL>
__global__ __launch_bounds__(512, 8) void node_fused_k(
    const unsigned short* __restrict__ hbf, const float* __restrict__ agg,
    const unsigned short* __restrict__ W1, const float* __restrict__ b1,
    const unsigned short* __restrict__ W2, const float* __restrict__ b2,
    const unsigned short* __restrict__ B3, const float* __restrict__ bias3,
    float* __restrict__ hFT, unsigned short* __restrict__ hB,
    unsigned short* __restrict__ Pout, float* __restrict__ outF,
    float* __restrict__ aggZ, int M)
{
    __shared__ unsigned short S[64 * SROW];
    const int tid = threadIdx.x;
    const int m0 = blockIdx.x * 64;
    const int wave = tid >> 6;
    const int lane = tid & 63;
    const int lrow = lane & 15;
    const int quad = lane >> 4;
    const int g = wave >> 1;          // row group 0..3
    const int h = wave & 1;           // N half
    const int row0 = m0 + g * 16 + quad * 4;
    const int elb = g * 16 + quad * 4;

    // agg A-fragments straight into registers (kt=4,5 of the K=192 A-op):
    // lane (g,lrow,quad) needs agg[m0+g*16+lrow][ktb*32 + quad*8 + 0..7]
    short8 afa0, afa1;
    {
        const float* ap = agg + (size_t)(m0 + g * 16 + lrow) * 64;
        floatx4 q0 = *(const floatx4*)(ap + quad * 8);
        floatx4 q1 = *(const floatx4*)(ap + quad * 8 + 4);
        floatx4 q2 = *(const floatx4*)(ap + 32 + quad * 8);
        floatx4 q3 = *(const floatx4*)(ap + 32 + quad * 8 + 4);
        unsigned int c0[4] = { f2bf_pk(q0[0], q0[1]), f2bf_pk(q0[2], q0[3]),
                               f2bf_pk(q1[0], q1[1]), f2bf_pk(q1[2], q1[3]) };
        unsigned int c1[4] = { f2bf_pk(q2[0], q2[1]), f2bf_pk(q2[2], q2[3]),
                               f2bf_pk(q3[0], q3[1]), f2bf_pk(q3[2], q3[3]) };
        afa0 = *(const short8*)c0;
        afa1 = *(const short8*)c1;
    }

    // residual prefetch: this wave's 4 feature-frags (transposed hFT, float4)
    floatx4 res4[4];
    #pragma unroll
    for (int j = 0; j < 4; j++) {
        int n = (4 * h + j) * 16 + lrow;
        res4[j] = *(const floatx4*)(hFT + (size_t)n * NR + row0);
    }

    // staging: h (128 bf16) only -> S cols 0..127
    for (int t = tid; t < 64 * 16; t += 512) {
        int rr = t >> 4, c = t & 15;
        int row = m0 + rr;
        uintx4 val = {0, 0, 0, 0};
        if (row < M) val = *(const uintx4*)(hbf + (size_t)row * 128 + c * 8);
        *(uintx4*)(&S[rr * SROW + c * 8]) = val;
    }
    __syncthreads();   // B1 (drains agg reads block-wide too)

    // zero this block's agg rows for the next layer (replaces hipMemsetAsync)
    if (!FINAL) {
        floatx4 z = {0, 0, 0, 0};
        for (int t = tid; t < 64 * 16; t += 512) {
            int rr = t >> 4, c = t & 15;
            int row = m0 + rr;
            if (row < M) *(floatx4*)(aggZ + (size_t)row * 64 + c * 4) = z;
        }
    }

    const unsigned short* arow = &S[(g * 16 + lrow) * SROW];

    // ---- phase A MFMA: K=192 (kt 0..3 from LDS, kt 4..5 from registers) ----
    floatx4 acc[4];
    #pragma unroll
    for (int i = 0; i < 4; i++) acc[i] = (floatx4){0, 0, 0, 0};
    #pragma unroll
    for (int kt = 0; kt < 4; kt++) {
        short8 afrag = *(const short8*)(arow + kt * 32 + quad * 8);
        int kb = kt * 4 + quad;
        #pragma unroll
        for (int j = 0; j < 4; j++) {
            int n = (4 * h + j) * 16 + lrow;
            short8 bfrag = *(const short8*)(W1 + (size_t)(kb * 128 + n) * 8);
            acc[j] = __builtin_amdgcn_mfma_f32_16x16x32_bf16(afrag, bfrag, acc[j], 0, 0, 0);
        }
    }
    #pragma unroll
    for (int j = 0; j < 4; j++) {
        int n = (4 * h + j) * 16 + lrow;
        short8 b4 = *(const short8*)(W1 + (size_t)((16 + quad) * 128 + n) * 8);
        acc[j] = __builtin_amdgcn_mfma_f32_16x16x32_bf16(afa0, b4, acc[j], 0, 0, 0);
        short8 b5 = *(const short8*)(W1 + (size_t)((20 + quad) * 128 + n) * 8);
        acc[j] = __builtin_amdgcn_mfma_f32_16x16x32_bf16(afa1, b5, acc[j], 0, 0, 0);
    }

    // epilogue A: t -> S cols 128..255
    #pragma unroll
    for (int j = 0; j < 4; j++) {
        int n = (4 * h + j) * 16 + lrow;
        float bv = b1[n];
        unsigned int p01 = f2bf_pk(silu_f(acc[j][0] + bv), silu_f(acc[j][1] + bv));
        unsigned int p23 = f2bf_pk(silu_f(acc[j][2] + bv), silu_f(acc[j][3] + bv));
        S[(elb + 0) * SROW + 128 + n] = (unsigned short)(p01 & 0xFFFF);
        S[(elb + 1) * SROW + 128 + n] = (unsigned short)(p01 >> 16);
        S[(elb + 2) * SROW + 128 + n] = (unsigned short)(p23 & 0xFFFF);
        S[(elb + 3) * SROW + 128 + n] = (unsigned short)(p23 >> 16);
    }
    __syncthreads();   // B2: t complete

    // ---- phase B MFMA: K=128 over t (cols 128..255) ----
    floatx4 acc2[4];
    #pragma unroll
    for (int i = 0; i < 4; i++) acc2[i] = (floatx4){0, 0, 0, 0};
    #pragma unroll
    for (int kt = 0; kt < 4; kt++) {
        short8 afrag = *(const short8*)(arow + 128 + kt * 32 + quad * 8);
        int kb = kt * 4 + quad;
        #pragma unroll
        for (int j = 0; j < 4; j++) {
            int n = (4 * h + j) * 16 + lrow;
            short8 bfrag = *(const short8*)(W2 + (size_t)(kb * 128 + n) * 8);
            acc2[j] = __builtin_amdgcn_mfma_f32_16x16x32_bf16(afrag, bfrag, acc2[j], 0, 0, 0);
        }
    }

    // epilogue B: h_new = acc2 + b2 + res -> S cols 0..127 + hFT (float4)
    #pragma unroll
    for (int j = 0; j < 4; j++) {
        int n = (4 * h + j) * 16 + lrow;
        float bv = b2[n];
        floatx4 v4;
        #pragma unroll
        for (int r = 0; r < 4; r++) v4[r] = acc2[j][r] + bv + res4[j][r];
        unsigned int p01 = f2bf_pk(v4[0], v4[1]);
        unsigned int p23 = f2bf_pk(v4[2], v4[3]);
        S[(elb + 0) * SROW + n] = (unsigned short)(p01 & 0xFFFF);
        S[(elb + 1) * SROW + n] = (unsigned short)(p01 >> 16);
        S[(elb + 2) * SROW + n] = (unsigned short)(p23 & 0xFFFF);
        S[(elb + 3) * SROW + n] = (unsigned short)(p23 >> 16);
        if (!FINAL && row0 < M)
            *(floatx4*)(hFT + (size_t)n * NR + row0) = v4;
    }
    __syncthreads();   // B3: h_new complete (all t reads done)

    // ---- phase C MFMA: K=128 -> P (128) or out (64) ----
    constexpr int NT3 = FINAL ? 2 : 4;
    constexpr int NO3 = FINAL ? 64 : 128;
    floatx4 acc3[NT3];
    #pragma unroll
    for (int i = 0; i < NT3; i++) acc3[i] = (floatx4){0, 0, 0, 0};
    #pragma unroll
    for (int kt = 0; kt < 4; kt++) {
        short8 afrag = *(const short8*)(arow + kt * 32 + quad * 8);
        int kb = kt * 4 + quad;
        #pragma unroll
        for (int j = 0; j < NT3; j++) {
            int n = (NT3 * h + j) * 16 + lrow;
            short8 bfrag = *(const short8*)(B3 + (size_t)(kb * NO3 + n) * 8);
            acc3[j] = __builtin_amdgcn_mfma_f32_16x16x32_bf16(afrag, bfrag, acc3[j], 0, 0, 0);
        }
    }
    // epilogue C -> S cols 128..255 (bf16 P) or fp32 out region (same cols)
    #pragma unroll
    for (int j = 0; j < NT3; j++) {
        int n = (NT3 * h + j) * 16 + lrow;
        float bv = bias3[n];
        if (FINAL) {
            #pragma unroll
            for (int r = 0; r < 4; r++)
                ((float*)(&S[(elb + r) * SROW + 128]))[n] = acc3[j][r] + bv;
        } else {
            unsigned int p01 = f2bf_pk(acc3[j][0] + bv, acc3[j][1] + bv);
            unsigned int p23 = f2bf_pk(acc3[j][2] + bv, acc3[j][3] + bv);
            S[(elb + 0) * SROW + 128 + n] = (unsigned short)(p01 & 0xFFFF);
            S[(elb + 1) * SROW + 128 + n] = (unsigned short)(p01 >> 16);
            S[(elb + 2) * SROW + 128 + n] = (unsigned short)(p23 & 0xFFFF);
            S[(elb + 3) * SROW + 128 + n] = (unsigned short)(p23 >> 16);
        }
    }
    __syncthreads();   // B4

    // cooperative wide stores
    if (FINAL) {
        for (int t = tid; t < 64 * 16; t += 512) {
            int rr = t >> 4, c = t & 15;
            int row = m0 + rr;
            if (row < M)
                *(floatx4*)(outF + (size_t)row * 64 + c * 4) =
                    *(const floatx4*)((const float*)(&S[rr * SROW + 128]) + c * 4);
        }
    } else {
        for (int t = tid; t < 64 * 32; t += 512) {
            int rr = t >> 5, c = t & 31;
            int row = m0 + rr;
            if (row < M) {
                if (c < 16)
                    *(uintx4*)(hB + (size_t)row * 128 + c * 8) =
                        *(const uintx4*)(&S[rr * SROW + c * 8]);
                else
                    *(uintx4*)(Pout + (size_t)row * 128 + (c - 16) * 8) =
                        *(const uintx4*)(&S[rr * SROW + 128 + (c - 16) * 8]);
            }
        }
    }
}

// ---------------------------------------------------------------------------
// Fused embedding (256 thr, wave-private rows, packed cvts) — unchanged R8
// ---------------------------------------------------------------------------
#define SROWE 264
__global__ __launch_bounds__(256) void embed_fused_k(
    const unsigned short* __restrict__ h0bf, const unsigned short* __restrict__ Win,
    const float* __restrict__ b_in, const unsigned short* __restrict__ W1,
    const float* __restrict__ biasP, float* __restrict__ hFT,
    unsigned short* __restrict__ hB, unsigned short* __restrict__ Pout, int M)
{
    __shared__ unsigned short S[64 * SROWE];
    const int tid = threadIdx.x;
    const int m0 = blockIdx.x * 64;
    const int wave = tid >> 6;
    const int lane = tid & 63;
    const int lrow = lane & 15;
    const int quad = lane >> 4;
    const int row0 = m0 + wave * 16 + quad * 4;
    const int elb = wave * 16 + quad * 4;

    for (int t = tid; t < 64 * 8; t += 256) {
        int rr = t >> 3, c = t & 7;
        int row = m0 + rr;
        uintx4 val = {0, 0, 0, 0};
        if (row < M) val = *(const uintx4*)(h0bf + (size_t)row * 64 + c * 8);
        *(uintx4*)(&S[rr * SROWE + c * 8]) = val;
    }
    __syncthreads();   // barrier 1

    const unsigned short* arow = &S[(wave * 16 + lrow) * SROWE];

    floatx4 acc[8];
    #pragma unroll
    for (int i = 0; i < 8; i++) acc[i] = (floatx4){0, 0, 0, 0};
    #pragma unroll
    for (int kt = 0; kt < 2; kt++) {
        short8 afrag = *(const short8*)(arow + kt * 32 + quad * 8);
        int kb = kt * 4 + quad;
        #pragma unroll
        for (int nt = 0; nt < 8; nt++) {
            short8 bfrag = *(const short8*)(Win + (size_t)(kb * 128 + nt * 16 + lrow) * 8);
            acc[nt] = __builtin_amdgcn_mfma_f32_16x16x32_bf16(afrag, bfrag, acc[nt], 0, 0, 0);
        }
    }

    // epilogue: h1 -> S cols 0..127 (bf16) + hFT float4 (wave-private rows)
    #pragma unroll
    for (int nt = 0; nt < 8; nt++) {
        int n = nt * 16 + lrow;
        float bv = b_in[n];
        floatx4 v4;
        #pragma unroll
        for (int r = 0; r < 4; r++) v4[r] = acc[nt][r] + bv;
        unsigned int p01 = f2bf_pk(v4[0], v4[1]);
        unsigned int p23 = f2bf_pk(v4[2], v4[3]);
        S[(elb + 0) * SROWE + n] = (unsigned short)(p01 & 0xFFFF);
        S[(elb + 1) * SROWE + n] = (unsigned short)(p01 >> 16);
        S[(elb + 2) * SROWE + n] = (unsigned short)(p23 & 0xFFFF);
        S[(elb + 3) * SROWE + n] = (unsigned short)(p23 >> 16);
        if (row0 < M)
            *(floatx4*)(hFT + (size_t)n * NR + row0) = v4;
    }

    floatx4 acc3[8];
    #pragma unroll
    for (int i = 0; i < 8; i++) acc3[i] = (floatx4){0, 0, 0, 0};
    #pragma unroll
    for (int kt = 0; kt < 4; kt++) {
        short8 afrag = *(const short8*)(arow + kt * 32 + quad * 8);
        int kb = kt * 4 + quad;
        #pragma unroll
        for (int nt = 0; nt < 8; nt++) {
            short8 bfrag = *(const short8*)(W1 + (size_t)(kb * 128 + nt * 16 + lrow) * 8);
            acc3[nt] = __builtin_amdgcn_mfma_f32_16x16x32_bf16(afrag, bfrag, acc3[nt], 0, 0, 0);
        }
    }
    #pragma unroll
    for (int nt = 0; nt < 8; nt++) {
        int n = nt * 16 + lrow;
        float bv = biasP[n];
        unsigned int p01 = f2bf_pk(acc3[nt][0] + bv, acc3[nt][1] + bv);
        unsigned int p23 = f2bf_pk(acc3[nt][2] + bv, acc3[nt][3] + bv);
        S[(elb + 0) * SROWE + 128 + n] = (unsigned short)(p01 & 0xFFFF);
        S[(elb + 1) * SROWE + 128 + n] = (unsigned short)(p01 >> 16);
        S[(elb + 2) * SROWE + 128 + n] = (unsigned short)(p23 & 0xFFFF);
        S[(elb + 3) * SROWE + 128 + n] = (unsigned short)(p23 >> 16);
    }
    __syncthreads();   // barrier 2

    for (int t = tid; t < 64 * 32; t += 256) {
        int rr = t / 32, c = t % 32;
        int row = m0 + rr;
        if (row < M) {
            if (c < 16)
                *(uintx4*)(hB + (size_t)row * 128 + c * 8) =
                    *(const uintx4*)(&S[rr * SROWE + c * 8]);
            else
                *(uintx4*)(Pout + (size_t)row * 128 + (c - 16) * 8) =
                    *(const uintx4*)(&S[rr * SROWE + 128 + (c - 16) * 8]);
        }
    }
}

// ---------------------------------------------------------------------------
extern "C" void kernel_launch(void* const* d_in, const int* in_sizes, int n_in,
                              void* d_out, int out_size, void* d_ws, size_t ws_size,
                              hipStream_t stream) {
    const float* h0   = (const float*)d_in[0];
    const int*   edges= (const int*)d_in[1];
    const float* W_in = (const float*)d_in[2];
    const float* b_in = (const float*)d_in[3];
    const float* eW1  = (const float*)d_in[4];
    const float* eb1  = (const float*)d_in[5];
    const float* eW2  = (const float*)d_in[6];
    const float* eb2  = (const float*)d_in[7];
    const float* nW1  = (const float*)d_in[8];
    const float* nb1  = (const float*)d_in[9];
    const float* nW2  = (const float*)d_in[10];
    const float* nb2  = (const float*)d_in[11];
    const float* W_out= (const float*)d_in[12];
    const float* b_out= (const float*)d_in[13];
    float* out = (float*)d_out;

    const int E = in_sizes[1] / 2;      // 800000
    const int* erow = edges;
    const int* ecol = edges + E;

    char* ws = (char*)d_ws;
    unsigned short* hbf  = (unsigned short*)(ws + 0);            // 12,800,000
    float*          hFT  = (float*)(ws + 12800000);              // 25,624,576 (128 x NR fp32)
    unsigned short* P    = (unsigned short*)(ws + 38424576);     // 12,800,000
    float*          agg  = (float*)(ws + 51224576);              // 12,800,000
    int2*           binned=(int2*)(ws + 51224576);               //  6,400,000 (aliases agg; consumed pre-zero)
    unsigned short* h0bf = (unsigned short*)(ws + 76824576);     //  6,400,000 (start only)
    int2*           eidx = (int2*)(ws + 76824576);               //  6,400,000 (aliases h0bf; written after embed)
    float*          biasP= (float*)(ws + 83224576);              //  2,048
    unsigned short* Winp = (unsigned short*)(ws + 83226624);     // 16,384
    unsigned short* Woutp= (unsigned short*)(ws + 83243008);     // 16,384
    unsigned short* W1p  = (unsigned short*)(ws + 83259392);     // 131,072
    unsigned short* eW2p = (unsigned short*)(ws + 83390464);     // 32,768
    unsigned short* nW1p = (unsigned short*)(ws + 83423232);     // 196,608
    unsigned short* nW2p = (unsigned short*)(ws + 83619840);     // 131,072
    int*            countB=(int*)(ws + 83750912);                // 784
    int*            bucketBase=(int*)(ws + 83751936);            // 788
    int*            bucketCursor=(int*)(ws + 83752960);          // 784

    const int gemm_grid = (N_NODES + 63) / 64;    // 782
    const int edge_grid = (E + 63) / 64;          // 12500
    const int pack_grid = (int)((PACK_TOTAL + 255) / 256);
    const int bin_grid  = (E + BCHUNK - 1) / BCHUNK;   // 391

    hipMemsetAsync(countB, 0, NBKT * 4, stream);
    pack_kernel<<<pack_grid, 256, 0, stream>>>(h0, W_in, W_out, eW1, eb1, eW2,
                                               nW1, nW2, h0bf, Winp, Woutp, W1p,
                                               eW2p, nW1p, nW2p, biasP);

    // binning before embed (binned aliases agg, unused until layers)
    hist_k<<<bin_grid, 256, 0, stream>>>(erow, countB, E);
    bucket_scan_k<<<1, 256, 0, stream>>>(countB, bucketBase, bucketCursor);
    bin_k<<<bin_grid, 256, 0, stream>>>(erow, ecol, bucketCursor, binned, E);

    // h1 = h0 @ W_in + b_in; P0 = h1 @ W1'[0]  (reads h0bf before eidx reuse)
    embed_fused_k<<<gemm_grid, 256, 0, stream>>>(
        h0bf, Winp, b_in, W1p, biasP, hFT, hbf, P, N_NODES);

    // sort after embed (eidx aliases h0bf); consumes binned (agg region)
    sort_k<<<NBKT, 256, 0, stream>>>(binned, bucketBase, eidx);

    // single agg zero for layer 0 (subsequent layers zeroed by node_fused)
    hipMemsetAsync(agg, 0, (size_t)N_NODES * 64 * 4, stream);

    for (int l = 0; l < 4; l++) {
        edge_fused_k<<<edge_grid, 256, 0, stream>>>(
            eidx, P, eW2p + (size_t)l * SE2, eb2 + (size_t)l * 64, agg, E);
        if (l < 3) {
            node_fused_k<0><<<gemm_grid, 512, 0, stream>>>(
                hbf, agg, nW1p + (size_t)l * SN1, nb1 + (size_t)l * 128,
                nW2p + (size_t)l * SN2, nb2 + (size_t)l * 128,
                W1p + (size_t)(l + 1) * SW1, biasP + (size_t)(l + 1) * 128,
                hFT, hbf, P, nullptr, agg, N_NODES);
        } else {
            node_fused_k<1><<<gemm_grid, 512, 0, stream>>>(
                hbf, agg, nW1p + (size_t)l * SN1, nb1 + (size_t)l * 128,
                nW2p + (size_t)l * SN2, nb2 + (size_t)l * 128,
                Woutp, b_out, hFT, hbf, nullptr, out, nullptr, N_NODES);
        }
    }
}

// Round 10
// 434.883 us; speedup vs baseline: 1.0646x; 1.0646x over previous
//
#include <hip/hip_runtime.h>
#include <hip/hip_bf16.h>
#include <cstdint>
#include <cstddef>

#define N_NODES 50000
#define N_EDGES 800000
#define NR      50048    // N_NODES rounded up (hFT row stride, floats)
#define NBKT    196      // ceil(50000/256) buckets of 256 rows
#define BSH     8        // rows-per-bucket shift
#define BCHUNK  2048     // edges per bin_k block
#define CAP     6144     // max edges per bucket (mean 4082)

typedef __attribute__((ext_vector_type(8))) short short8;
typedef __attribute__((ext_vector_type(4))) float floatx4;
typedef __attribute__((ext_vector_type(4))) unsigned int uintx4;

__device__ inline float bf2f(unsigned short u) {
    union { unsigned int i; float f; } v; v.i = ((unsigned int)u) << 16; return v.f;
}
__device__ inline unsigned short f2bf(float f) {
    union { float f; unsigned int i; } v; v.f = f;
    unsigned int u = v.i;
    return (unsigned short)((u + 0x7FFFu + ((u >> 16) & 1u)) >> 16);
}
// packed RNE f32x2 -> bf16x2 (v_cvt_pk_bf16_f32 on gfx950)
__device__ inline unsigned int f2bf_pk(float a, float b) {
    __hip_bfloat162 h2 = __float22bfloat162_rn(make_float2(a, b));
    return *reinterpret_cast<unsigned int*>(&h2);
}
// unpack 2 bf16 (packed in a uint) to 2 floats
__device__ inline float2 bf2f2(unsigned int u) {
    union { unsigned int i; float f; } lo, hi;
    lo.i = u << 16;
    hi.i = u & 0xFFFF0000u;
    return make_float2(lo.f, hi.f);
}
// silu via v_rcp_f32 (1 ulp) instead of IEEE divide
__device__ inline float silu_f(float x) {
    float e = __expf(-x);
    return x * __builtin_amdgcn_rcpf(1.0f + e);
}

__device__ inline int block_excl_scan_256(int v, int* buf) {
    int tid = threadIdx.x;
    buf[tid] = v;
    __syncthreads();
    #pragma unroll
    for (int off = 1; off < 256; off <<= 1) {
        int t = (tid >= off) ? buf[tid - off] : 0;
        __syncthreads();
        buf[tid] += t;
        __syncthreads();
    }
    return buf[tid] - v;
}

// ---------------------------------------------------------------------------
// Pack kernel: fp32->bf16 conversions + weight rearrangement into MFMA
// B-fragment order: Bp[(kb*NOUT + n)*8 + i] = B[(kb*8+i)*NOUT + n]
// ---------------------------------------------------------------------------
__device__ inline void pack_std(const float* __restrict__ src,
                                unsigned short* __restrict__ dst,
                                int NOUT, long j) {
    int i = (int)(j & 7);
    long rest = j >> 3;
    int n = (int)(rest % NOUT);
    int kb = (int)(rest / NOUT);
    dst[j] = f2bf(src[(long)(kb * 8 + i) * NOUT + n]);
}

#define NH0   (N_NODES * 64L)
#define SW_IN 8192L
#define SW_OUT 8192L
#define SW1   16384L
#define SE2   4096L
#define SN1   24576L
#define SN2   16384L
#define SB    128L
#define PERL  (SW1 + SE2 + SN1 + SN2 + SB)
#define PACK_TOTAL (NH0 + SW_IN + SW_OUT + 4 * PERL)

__global__ __launch_bounds__(256) void pack_kernel(
    const float* __restrict__ h0, const float* __restrict__ W_in,
    const float* __restrict__ W_out, const float* __restrict__ eW1,
    const float* __restrict__ eb1, const float* __restrict__ eW2,
    const float* __restrict__ nW1, const float* __restrict__ nW2,
    unsigned short* __restrict__ h0bf, unsigned short* __restrict__ Winp,
    unsigned short* __restrict__ Woutp, unsigned short* __restrict__ W1p,
    unsigned short* __restrict__ eW2p, unsigned short* __restrict__ nW1p,
    unsigned short* __restrict__ nW2p, float* __restrict__ biasP)
{
    long idx = (long)blockIdx.x * 256 + threadIdx.x;
    if (idx >= PACK_TOTAL) return;
    long j = idx;
    if (j < NH0) { h0bf[j] = f2bf(h0[j]); return; }
    j -= NH0;
    if (j < SW_IN) { pack_std(W_in, Winp, 128, j); return; }
    j -= SW_IN;
    if (j < SW_OUT) { pack_std(W_out, Woutp, 64, j); return; }
    j -= SW_OUT;
    int l = (int)(j / PERL);
    long r = j % PERL;
    if (r < SW1) {
        int i = (int)(r & 7);
        int n = (int)((r >> 3) & 127);
        int kb = (int)(r >> 10);
        int k = kb * 8 + i;
        const float* w = eW1 + (long)l * 256 * 64;
        float v = (n < 64) ? w[(long)k * 64 + n] : w[(long)(128 + k) * 64 + (n - 64)];
        W1p[(long)l * SW1 + r] = f2bf(v);
        return;
    }
    r -= SW1;
    if (r < SE2) { pack_std(eW2 + (long)l * 4096, eW2p + (long)l * SE2, 64, r); return; }
    r -= SE2;
    if (r < SN1) { pack_std(nW1 + (long)l * 24576, nW1p + (long)l * SN1, 128, r); return; }
    r -= SN1;
    if (r < SN2) { pack_std(nW2 + (long)l * 16384, nW2p + (long)l * SN2, 128, r); return; }
    r -= SN2;
    biasP[(long)l * 128 + r] = (r < 64) ? eb1[(long)l * 64 + r] : 0.0f;
}

// ---------------------------------------------------------------------------
// Edge-sort pipeline
// ---------------------------------------------------------------------------
__global__ __launch_bounds__(256) void hist_k(const int* __restrict__ erow,
                                              int* __restrict__ countB, int E) {
    __shared__ int c[NBKT];
    for (int i = threadIdx.x; i < NBKT; i += 256) c[i] = 0;
    __syncthreads();
    int j = blockIdx.x * BCHUNK + threadIdx.x;
    #pragma unroll
    for (int i = 0; i < BCHUNK / 256; i++, j += 256)
        if (j < E) atomicAdd(&c[erow[j] >> BSH], 1);
    __syncthreads();
    for (int i = threadIdx.x; i < NBKT; i += 256)
        if (c[i]) atomicAdd(&countB[i], c[i]);
}

__global__ __launch_bounds__(256) void bucket_scan_k(const int* __restrict__ countB,
                                                     int* __restrict__ bucketBase,
                                                     int* __restrict__ bucketCursor) {
    __shared__ int buf[256];
    int tid = threadIdx.x;
    int v = (tid < NBKT) ? countB[tid] : 0;
    int excl = block_excl_scan_256(v, buf);
    if (tid < NBKT) {
        bucketBase[tid] = excl;
        bucketCursor[tid] = excl;
    }
    if (tid == NBKT - 1) bucketBase[NBKT] = excl + v;   // = E
}

__global__ __launch_bounds__(256) void bin_k(
    const int* __restrict__ erow, const int* __restrict__ ecol,
    int* __restrict__ bucketCursor, int2* __restrict__ binned, int E)
{
    __shared__ int2 staged[BCHUNK];
    __shared__ int cnt[NBKT];
    __shared__ int binStart[NBKT];
    __shared__ int gbase[NBKT];
    __shared__ int scanbuf[256];
    const int tid = threadIdx.x;
    const int base = blockIdx.x * BCHUNK;
    const int nloc = min(BCHUNK, E - base);

    for (int i = tid; i < NBKT; i += 256) cnt[i] = 0;
    __syncthreads();

    int2 ed[BCHUNK / 256];
    int  bo[BCHUNK / 256];
    #pragma unroll
    for (int i = 0; i < BCHUNK / 256; i++) {
        int jl = i * 256 + tid;
        if (jl < nloc) {
            int j = base + jl;
            int r = erow[j], c = ecol[j];
            ed[i] = make_int2(r, c);
            int b = r >> BSH;
            int off = atomicAdd(&cnt[b], 1);
            bo[i] = (b << 12) | off;
        } else bo[i] = -1;
    }
    __syncthreads();

    int v = (tid < NBKT) ? cnt[tid] : 0;
    int excl = block_excl_scan_256(v, scanbuf);
    if (tid < NBKT) binStart[tid] = excl;
    if (tid < NBKT && v > 0) gbase[tid] = atomicAdd(&bucketCursor[tid], v);
    __syncthreads();

    #pragma unroll
    for (int i = 0; i < BCHUNK / 256; i++) {
        if (bo[i] >= 0)
            staged[binStart[bo[i] >> 12] + (bo[i] & 0xFFF)] = ed[i];
    }
    __syncthreads();

    for (int j = tid; j < nloc; j += 256) {
        int2 e = staged[j];
        int b = e.x >> BSH;
        binned[gbase[b] + (j - binStart[b])] = e;
    }
}

__global__ __launch_bounds__(256) void sort_k(
    const int2* __restrict__ binned, const int* __restrict__ bucketBase,
    int2* __restrict__ eidx)
{
    __shared__ int2 st[CAP];
    __shared__ int cnt[256];
    __shared__ int cur[256];
    __shared__ int scanbuf[256];
    const int b = blockIdx.x;
    const int tid = threadIdx.x;
    const int s0 = bucketBase[b];
    int n = bucketBase[b + 1] - s0;
    if (n > CAP) n = CAP;

    cnt[tid] = 0;
    __syncthreads();
    for (int j = tid; j < n; j += 256) {
        int2 e = binned[s0 + j];
        st[j] = e;
        atomicAdd(&cnt[e.x & 255], 1);
    }
    __syncthreads();
    int excl = block_excl_scan_256(cnt[tid], scanbuf);
    cur[tid] = excl;
    __syncthreads();
    for (int j = tid; j < n; j += 256) {
        int2 e = st[j];
        int pos = atomicAdd(&cur[e.x & 255], 1);
        eidx[s0 + pos] = e;
    }
}

// ---------------------------------------------------------------------------
// Fused edge + block-segmented aggregate over sorted edges (unchanged).
// ---------------------------------------------------------------------------
__global__ __launch_bounds__(256) void edge_fused_k(
    const int2* __restrict__ eidx,
    const unsigned short* __restrict__ P,    // [N,128]: 0..63 top(+b1), 64..127 bot
    const unsigned short* __restrict__ Bp,   // eW2 frag order
    const float* __restrict__ b2, float* __restrict__ agg, int E)
{
    __shared__ float M2s[64 * 68];
    __shared__ int ridS[64];
    __shared__ short segStartS[66];
    __shared__ int nsegS;
    const int tid = threadIdx.x;
    const int wave = tid >> 6;
    const int lane = tid & 63;
    const int lrow = lane & 15;
    const int quad = lane >> 4;
    const int e0 = blockIdx.x * 64;
    const int el = wave * 16 + lrow;
    const int e = e0 + el;

    short8 af0 = {0, 0, 0, 0, 0, 0, 0, 0};
    short8 af1 = af0;
    if (e < E) {
        int2 rc = eidx[e];
        int rr = rc.x, cc = rc.y;
        if (quad == 0) ridS[el] = rr;
        const uintx4* pt = (const uintx4*)(P + (size_t)rr * 128 + quad * 8);
        const uintx4* pb = (const uintx4*)(P + (size_t)cc * 128 + 64 + quad * 8);
        uintx4 t0 = pt[0], t1 = pt[4];
        uintx4 b0 = pb[0], b1 = pb[4];
        const unsigned int* t0u = (const unsigned int*)&t0;
        const unsigned int* t1u = (const unsigned int*)&t1;
        const unsigned int* b0u = (const unsigned int*)&b0;
        const unsigned int* b1u = (const unsigned int*)&b1;
        unsigned int o0[4], o1[4];
        #pragma unroll
        for (int i = 0; i < 4; i++) {
            float2 a0 = bf2f2(t0u[i]), c0 = bf2f2(b0u[i]);
            o0[i] = f2bf_pk(silu_f(a0.x + c0.x), silu_f(a0.y + c0.y));
            float2 a1 = bf2f2(t1u[i]), c1 = bf2f2(b1u[i]);
            o1[i] = f2bf_pk(silu_f(a1.x + c1.x), silu_f(a1.y + c1.y));
        }
        af0 = *(const short8*)o0;
        af1 = *(const short8*)o1;
    } else if (quad == 0) {
        ridS[el] = -1;
    }

    floatx4 acc[4];
    #pragma unroll
    for (int i = 0; i < 4; i++) acc[i] = (floatx4){0, 0, 0, 0};
    #pragma unroll
    for (int nt = 0; nt < 4; nt++) {
        short8 bf0 = *(const short8*)(Bp + (size_t)((0 * 4 + quad) * 64 + nt * 16 + lrow) * 8);
        acc[nt] = __builtin_amdgcn_mfma_f32_16x16x32_bf16(af0, bf0, acc[nt], 0, 0, 0);
        short8 bf1 = *(const short8*)(Bp + (size_t)((1 * 4 + quad) * 64 + nt * 16 + lrow) * 8);
        acc[nt] = __builtin_amdgcn_mfma_f32_16x16x32_bf16(af1, bf1, acc[nt], 0, 0, 0);
    }

    #pragma unroll
    for (int nt = 0; nt < 4; nt++) {
        int n = nt * 16 + lrow;
        float bv = b2[n];
        #pragma unroll
        for (int r = 0; r < 4; r++) {
            int el2 = wave * 16 + quad * 4 + r;
            M2s[el2 * 68 + n] = silu_f(acc[nt][r] + bv);
        }
    }
    __syncthreads();

    if (tid < 64) {
        bool st = (ridS[tid] >= 0) && (tid == 0 || ridS[tid] != ridS[tid - 1]);
        unsigned long long m = __ballot(st);
        if (st) {
            int pos = __popcll(m & ((1ull << tid) - 1));
            segStartS[pos] = (short)tid;
        }
        if (tid == 0) {
            int ns = __popcll(m);
            nsegS = ns;
            int nvalid = E - e0;
            if (nvalid > 64) nvalid = 64;
            segStartS[ns] = (short)nvalid;
        }
    }
    __syncthreads();

    {
        int f = tid & 63;
        int g = tid >> 6;
        int ns = nsegS;
        for (int j = g; j < ns; j += 4) {
            int a = segStartS[j], b = segStartS[j + 1];
            float s = 0.0f;
            for (int el2 = a; el2 < b; el2++) s += M2s[el2 * 68 + f];
            int rv = ridS[a];
            if (j == 0 || j == ns - 1)
                atomicAdd(&agg[(size_t)rv * 64 + f], s);
            else
                agg[(size_t)rv * 64 + f] = s;
        }
    }
}

// ---------------------------------------------------------------------------
// Fused node-side chain, R10: R9 structure (register agg A-frags, SROW 264,
// LDS 33792 B) but WITHOUT the forced occupancy bound — R9's (512,8) caused
// scratch spills (VGPR 32, WRITE +40MB). Plain 512: compiler ~84 VGPR, 0 spill.
// ---------------------------------------------------------------------------
#define SROW 264
template<int FINAL>
__global__ __launch_bounds__(512) void node_fused_k(
    const unsigned short* __restrict__ hbf, const float* __restrict__ agg,
    const unsigned short* __restrict__ W1, const float* __restrict__ b1,
    const unsigned short* __restrict__ W2, const float* __restrict__ b2,
    const unsigned short* __restrict__ B3, const float* __restrict__ bias3,
    float* __restrict__ hFT, unsigned short* __restrict__ hB,
    unsigned short* __restrict__ Pout, float* __restrict__ outF,
    float* __restrict__ aggZ, int M)
{
    __shared__ unsigned short S[64 * SROW];
    const int tid = threadIdx.x;
    const int m0 = blockIdx.x * 64;
    const int wave = tid >> 6;
    const int lane = tid & 63;
    const int lrow = lane & 15;
    const int quad = lane >> 4;
    const int g = wave >> 1;          // row group 0..3
    const int h = wave & 1;           // N half
    const int row0 = m0 + g * 16 + quad * 4;
    const int elb = g * 16 + quad * 4;

    // agg A-fragments straight into registers (kt=4,5 of the K=192 A-op)
    short8 afa0, afa1;
    {
        const float* ap = agg + (size_t)(m0 + g * 16 + lrow) * 64;
        floatx4 q0 = *(const floatx4*)(ap + quad * 8);
        floatx4 q1 = *(const floatx4*)(ap + quad * 8 + 4);
        floatx4 q2 = *(const floatx4*)(ap + 32 + quad * 8);
        floatx4 q3 = *(const floatx4*)(ap + 32 + quad * 8 + 4);
        unsigned int c0[4] = { f2bf_pk(q0[0], q0[1]), f2bf_pk(q0[2], q0[3]),
                               f2bf_pk(q1[0], q1[1]), f2bf_pk(q1[2], q1[3]) };
        unsigned int c1[4] = { f2bf_pk(q2[0], q2[1]), f2bf_pk(q2[2], q2[3]),
                               f2bf_pk(q3[0], q3[1]), f2bf_pk(q3[2], q3[3]) };
        afa0 = *(const short8*)c0;
        afa1 = *(const short8*)c1;
    }

    // residual prefetch: this wave's 4 feature-frags (transposed hFT, float4)
    floatx4 res4[4];
    #pragma unroll
    for (int j = 0; j < 4; j++) {
        int n = (4 * h + j) * 16 + lrow;
        res4[j] = *(const floatx4*)(hFT + (size_t)n * NR + row0);
    }

    // staging: h (128 bf16) only -> S cols 0..127
    for (int t = tid; t < 64 * 16; t += 512) {
        int rr = t >> 4, c = t & 15;
        int row = m0 + rr;
        uintx4 val = {0, 0, 0, 0};
        if (row < M) val = *(const uintx4*)(hbf + (size_t)row * 128 + c * 8);
        *(uintx4*)(&S[rr * SROW + c * 8]) = val;
    }
    __syncthreads();   // B1

    // zero this block's agg rows for the next layer (replaces hipMemsetAsync)
    if (!FINAL) {
        floatx4 z = {0, 0, 0, 0};
        for (int t = tid; t < 64 * 16; t += 512) {
            int rr = t >> 4, c = t & 15;
            int row = m0 + rr;
            if (row < M) *(floatx4*)(aggZ + (size_t)row * 64 + c * 4) = z;
        }
    }

    const unsigned short* arow = &S[(g * 16 + lrow) * SROW];

    // ---- phase A MFMA: K=192 (kt 0..3 from LDS, kt 4..5 from registers) ----
    floatx4 acc[4];
    #pragma unroll
    for (int i = 0; i < 4; i++) acc[i] = (floatx4){0, 0, 0, 0};
    #pragma unroll
    for (int kt = 0; kt < 4; kt++) {
        short8 afrag = *(const short8*)(arow + kt * 32 + quad * 8);
        int kb = kt * 4 + quad;
        #pragma unroll
        for (int j = 0; j < 4; j++) {
            int n = (4 * h + j) * 16 + lrow;
            short8 bfrag = *(const short8*)(W1 + (size_t)(kb * 128 + n) * 8);
            acc[j] = __builtin_amdgcn_mfma_f32_16x16x32_bf16(afrag, bfrag, acc[j], 0, 0, 0);
        }
    }
    #pragma unroll
    for (int j = 0; j < 4; j++) {
        int n = (4 * h + j) * 16 + lrow;
        short8 b4 = *(const short8*)(W1 + (size_t)((16 + quad) * 128 + n) * 8);
        acc[j] = __builtin_amdgcn_mfma_f32_16x16x32_bf16(afa0, b4, acc[j], 0, 0, 0);
        short8 b5 = *(const short8*)(W1 + (size_t)((20 + quad) * 128 + n) * 8);
        acc[j] = __builtin_amdgcn_mfma_f32_16x16x32_bf16(afa1, b5, acc[j], 0, 0, 0);
    }

    // epilogue A: t -> S cols 128..255
    #pragma unroll
    for (int j = 0; j < 4; j++) {
        int n = (4 * h + j) * 16 + lrow;
        float bv = b1[n];
        unsigned int p01 = f2bf_pk(silu_f(acc[j][0] + bv), silu_f(acc[j][1] + bv));
        unsigned int p23 = f2bf_pk(silu_f(acc[j][2] + bv), silu_f(acc[j][3] + bv));
        S[(elb + 0) * SROW + 128 + n] = (unsigned short)(p01 & 0xFFFF);
        S[(elb + 1) * SROW + 128 + n] = (unsigned short)(p01 >> 16);
        S[(elb + 2) * SROW + 128 + n] = (unsigned short)(p23 & 0xFFFF);
        S[(elb + 3) * SROW + 128 + n] = (unsigned short)(p23 >> 16);
    }
    __syncthreads();   // B2: t complete

    // ---- phase B MFMA: K=128 over t (cols 128..255) ----
    floatx4 acc2[4];
    #pragma unroll
    for (int i = 0; i < 4; i++) acc2[i] = (floatx4){0, 0, 0, 0};
    #pragma unroll
    for (int kt = 0; kt < 4; kt++) {
        short8 afrag = *(const short8*)(arow + 128 + kt * 32 + quad * 8);
        int kb = kt * 4 + quad;
        #pragma unroll
        for (int j = 0; j < 4; j++) {
            int n = (4 * h + j) * 16 + lrow;
            short8 bfrag = *(const short8*)(W2 + (size_t)(kb * 128 + n) * 8);
            acc2[j] = __builtin_amdgcn_mfma_f32_16x16x32_bf16(afrag, bfrag, acc2[j], 0, 0, 0);
        }
    }

    // epilogue B: h_new = acc2 + b2 + res -> S cols 0..127 + hFT (float4)
    #pragma unroll
    for (int j = 0; j < 4; j++) {
        int n = (4 * h + j) * 16 + lrow;
        float bv = b2[n];
        floatx4 v4;
        #pragma unroll
        for (int r = 0; r < 4; r++) v4[r] = acc2[j][r] + bv + res4[j][r];
        unsigned int p01 = f2bf_pk(v4[0], v4[1]);
        unsigned int p23 = f2bf_pk(v4[2], v4[3]);
        S[(elb + 0) * SROW + n] = (unsigned short)(p01 & 0xFFFF);
        S[(elb + 1) * SROW + n] = (unsigned short)(p01 >> 16);
        S[(elb + 2) * SROW + n] = (unsigned short)(p23 & 0xFFFF);
        S[(elb + 3) * SROW + n] = (unsigned short)(p23 >> 16);
        if (!FINAL && row0 < M)
            *(floatx4*)(hFT + (size_t)n * NR + row0) = v4;
    }
    __syncthreads();   // B3: h_new complete (all t reads done)

    // ---- phase C MFMA: K=128 -> P (128) or out (64) ----
    constexpr int NT3 = FINAL ? 2 : 4;
    constexpr int NO3 = FINAL ? 64 : 128;
    floatx4 acc3[NT3];
    #pragma unroll
    for (int i = 0; i < NT3; i++) acc3[i] = (floatx4){0, 0, 0, 0};
    #pragma unroll
    for (int kt = 0; kt < 4; kt++) {
        short8 afrag = *(const short8*)(arow + kt * 32 + quad * 8);
        int kb = kt * 4 + quad;
        #pragma unroll
        for (int j = 0; j < NT3; j++) {
            int n = (NT3 * h + j) * 16 + lrow;
            short8 bfrag = *(const short8*)(B3 + (size_t)(kb * NO3 + n) * 8);
            acc3[j] = __builtin_amdgcn_mfma_f32_16x16x32_bf16(afrag, bfrag, acc3[j], 0, 0, 0);
        }
    }
    // epilogue C -> S cols 128..255 (bf16 P) or fp32 out region (same cols)
    #pragma unroll
    for (int j = 0; j < NT3; j++) {
        int n = (NT3 * h + j) * 16 + lrow;
        float bv = bias3[n];
        if (FINAL) {
            #pragma unroll
            for (int r = 0; r < 4; r++)
                ((float*)(&S[(elb + r) * SROW + 128]))[n] = acc3[j][r] + bv;
        } else {
            unsigned int p01 = f2bf_pk(acc3[j][0] + bv, acc3[j][1] + bv);
            unsigned int p23 = f2bf_pk(acc3[j][2] + bv, acc3[j][3] + bv);
            S[(elb + 0) * SROW + 128 + n] = (unsigned short)(p01 & 0xFFFF);
            S[(elb + 1) * SROW + 128 + n] = (unsigned short)(p01 >> 16);
            S[(elb + 2) * SROW + 128 + n] = (unsigned short)(p23 & 0xFFFF);
            S[(elb + 3) * SROW + 128 + n] = (unsigned short)(p23 >> 16);
        }
    }
    __syncthreads();   // B4

    // cooperative wide stores
    if (FINAL) {
        for (int t = tid; t < 64 * 16; t += 512) {
            int rr = t >> 4, c = t & 15;
            int row = m0 + rr;
            if (row < M)
                *(floatx4*)(outF + (size_t)row * 64 + c * 4) =
                    *(const floatx4*)((const float*)(&S[rr * SROW + 128]) + c * 4);
        }
    } else {
        for (int t = tid; t < 64 * 32; t += 512) {
            int rr = t >> 5, c = t & 31;
            int row = m0 + rr;
            if (row < M) {
                if (c < 16)
                    *(uintx4*)(hB + (size_t)row * 128 + c * 8) =
                        *(const uintx4*)(&S[rr * SROW + c * 8]);
                else
                    *(uintx4*)(Pout + (size_t)row * 128 + (c - 16) * 8) =
                        *(const uintx4*)(&S[rr * SROW + 128 + (c - 16) * 8]);
            }
        }
    }
}

// ---------------------------------------------------------------------------
// Fused embedding (256 thr, wave-private rows, packed cvts)
// ---------------------------------------------------------------------------
#define SROWE 264
__global__ __launch_bounds__(256) void embed_fused_k(
    const unsigned short* __restrict__ h0bf, const unsigned short* __restrict__ Win,
    const float* __restrict__ b_in, const unsigned short* __restrict__ W1,
    const float* __restrict__ biasP, float* __restrict__ hFT,
    unsigned short* __restrict__ hB, unsigned short* __restrict__ Pout, int M)
{
    __shared__ unsigned short S[64 * SROWE];
    const int tid = threadIdx.x;
    const int m0 = blockIdx.x * 64;
    const int wave = tid >> 6;
    const int lane = tid & 63;
    const int lrow = lane & 15;
    const int quad = lane >> 4;
    const int row0 = m0 + wave * 16 + quad * 4;
    const int elb = wave * 16 + quad * 4;

    for (int t = tid; t < 64 * 8; t += 256) {
        int rr = t >> 3, c = t & 7;
        int row = m0 + rr;
        uintx4 val = {0, 0, 0, 0};
        if (row < M) val = *(const uintx4*)(h0bf + (size_t)row * 64 + c * 8);
        *(uintx4*)(&S[rr * SROWE + c * 8]) = val;
    }
    __syncthreads();   // barrier 1

    const unsigned short* arow = &S[(wave * 16 + lrow) * SROWE];

    floatx4 acc[8];
    #pragma unroll
    for (int i = 0; i < 8; i++) acc[i] = (floatx4){0, 0, 0, 0};
    #pragma unroll
    for (int kt = 0; kt < 2; kt++) {
        short8 afrag = *(const short8*)(arow + kt * 32 + quad * 8);
        int kb = kt * 4 + quad;
        #pragma unroll
        for (int nt = 0; nt < 8; nt++) {
            short8 bfrag = *(const short8*)(Win + (size_t)(kb * 128 + nt * 16 + lrow) * 8);
            acc[nt] = __builtin_amdgcn_mfma_f32_16x16x32_bf16(afrag, bfrag, acc[nt], 0, 0, 0);
        }
    }

    // epilogue: h1 -> S cols 0..127 (bf16) + hFT float4 (wave-private rows)
    #pragma unroll
    for (int nt = 0; nt < 8; nt++) {
        int n = nt * 16 + lrow;
        float bv = b_in[n];
        floatx4 v4;
        #pragma unroll
        for (int r = 0; r < 4; r++) v4[r] = acc[nt][r] + bv;
        unsigned int p01 = f2bf_pk(v4[0], v4[1]);
        unsigned int p23 = f2bf_pk(v4[2], v4[3]);
        S[(elb + 0) * SROWE + n] = (unsigned short)(p01 & 0xFFFF);
        S[(elb + 1) * SROWE + n] = (unsigned short)(p01 >> 16);
        S[(elb + 2) * SROWE + n] = (unsigned short)(p23 & 0xFFFF);
        S[(elb + 3) * SROWE + n] = (unsigned short)(p23 >> 16);
        if (row0 < M)
            *(floatx4*)(hFT + (size_t)n * NR + row0) = v4;
    }

    floatx4 acc3[8];
    #pragma unroll
    for (int i = 0; i < 8; i++) acc3[i] = (floatx4){0, 0, 0, 0};
    #pragma unroll
    for (int kt = 0; kt < 4; kt++) {
        short8 afrag = *(const short8*)(arow + kt * 32 + quad * 8);
        int kb = kt * 4 + quad;
        #pragma unroll
        for (int nt = 0; nt < 8; nt++) {
            short8 bfrag = *(const short8*)(W1 + (size_t)(kb * 128 + nt * 16 + lrow) * 8);
            acc3[nt] = __builtin_amdgcn_mfma_f32_16x16x32_bf16(afrag, bfrag, acc3[nt], 0, 0, 0);
        }
    }
    #pragma unroll
    for (int nt = 0; nt < 8; nt++) {
        int n = nt * 16 + lrow;
        float bv = biasP[n];
        unsigned int p01 = f2bf_pk(acc3[nt][0] + bv, acc3[nt][1] + bv);
        unsigned int p23 = f2bf_pk(acc3[nt][2] + bv, acc3[nt][3] + bv);
        S[(elb + 0) * SROWE + 128 + n] = (unsigned short)(p01 & 0xFFFF);
        S[(elb + 1) * SROWE + 128 + n] = (unsigned short)(p01 >> 16);
        S[(elb + 2) * SROWE + 128 + n] = (unsigned short)(p23 & 0xFFFF);
        S[(elb + 3) * SROWE + 128 + n] = (unsigned short)(p23 >> 16);
    }
    __syncthreads();   // barrier 2

    for (int t = tid; t < 64 * 32; t += 256) {
        int rr = t / 32, c = t % 32;
        int row = m0 + rr;
        if (row < M) {
            if (c < 16)
                *(uintx4*)(hB + (size_t)row * 128 + c * 8) =
                    *(const uintx4*)(&S[rr * SROWE + c * 8]);
            else
                *(uintx4*)(Pout + (size_t)row * 128 + (c - 16) * 8) =
                    *(const uintx4*)(&S[rr * SROWE + 128 + (c - 16) * 8]);
        }
    }
}

// ---------------------------------------------------------------------------
extern "C" void kernel_launch(void* const* d_in, const int* in_sizes, int n_in,
                              void* d_out, int out_size, void* d_ws, size_t ws_size,
                              hipStream_t stream) {
    const float* h0   = (const float*)d_in[0];
    const int*   edges= (const int*)d_in[1];
    const float* W_in = (const float*)d_in[2];
    const float* b_in = (const float*)d_in[3];
    const float* eW1  = (const float*)d_in[4];
    const float* eb1  = (const float*)d_in[5];
    const float* eW2  = (const float*)d_in[6];
    const float* eb2  = (const float*)d_in[7];
    const float* nW1  = (const float*)d_in[8];
    const float* nb1  = (const float*)d_in[9];
    const float* nW2  = (const float*)d_in[10];
    const float* nb2  = (const float*)d_in[11];
    const float* W_out= (const float*)d_in[12];
    const float* b_out= (const float*)d_in[13];
    float* out = (float*)d_out;

    const int E = in_sizes[1] / 2;      // 800000
    const int* erow = edges;
    const int* ecol = edges + E;

    char* ws = (char*)d_ws;
    unsigned short* hbf  = (unsigned short*)(ws + 0);            // 12,800,000
    float*          hFT  = (float*)(ws + 12800000);              // 25,624,576 (128 x NR fp32)
    unsigned short* P    = (unsigned short*)(ws + 38424576);     // 12,800,000
    float*          agg  = (float*)(ws + 51224576);              // 12,800,000
    int2*           binned=(int2*)(ws + 51224576);               //  6,400,000 (aliases agg; consumed pre-zero)
    unsigned short* h0bf = (unsigned short*)(ws + 76824576);     //  6,400,000 (start only)
    int2*           eidx = (int2*)(ws + 76824576);               //  6,400,000 (aliases h0bf; written after embed)
    float*          biasP= (float*)(ws + 83224576);              //  2,048
    unsigned short* Winp = (unsigned short*)(ws + 83226624);     // 16,384
    unsigned short* Woutp= (unsigned short*)(ws + 83243008);     // 16,384
    unsigned short* W1p  = (unsigned short*)(ws + 83259392);     // 131,072
    unsigned short* eW2p = (unsigned short*)(ws + 83390464);     // 32,768
    unsigned short* nW1p = (unsigned short*)(ws + 83423232);     // 196,608
    unsigned short* nW2p = (unsigned short*)(ws + 83619840);     // 131,072
    int*            countB=(int*)(ws + 83750912);                // 784
    int*            bucketBase=(int*)(ws + 83751936);            // 788
    int*            bucketCursor=(int*)(ws + 83752960);          // 784

    const int gemm_grid = (N_NODES + 63) / 64;    // 782
    const int edge_grid = (E + 63) / 64;          // 12500
    const int pack_grid = (int)((PACK_TOTAL + 255) / 256);
    const int bin_grid  = (E + BCHUNK - 1) / BCHUNK;   // 391

    hipMemsetAsync(countB, 0, NBKT * 4, stream);
    pack_kernel<<<pack_grid, 256, 0, stream>>>(h0, W_in, W_out, eW1, eb1, eW2,
                                               nW1, nW2, h0bf, Winp, Woutp, W1p,
                                               eW2p, nW1p, nW2p, biasP);

    // binning before embed (binned aliases agg, unused until layers)
    hist_k<<<bin_grid, 256, 0, stream>>>(erow, countB, E);
    bucket_scan_k<<<1, 256, 0, stream>>>(countB, bucketBase, bucketCursor);
    bin_k<<<bin_grid, 256, 0, stream>>>(erow, ecol, bucketCursor, binned, E);

    // h1 = h0 @ W_in + b_in; P0 = h1 @ W1'[0]  (reads h0bf before eidx reuse)
    embed_fused_k<<<gemm_grid, 256, 0, stream>>>(
        h0bf, Winp, b_in, W1p, biasP, hFT, hbf, P, N_NODES);

    // sort after embed (eidx aliases h0bf); consumes binned (agg region)
    sort_k<<<NBKT, 256, 0, stream>>>(binned, bucketBase, eidx);

    // single agg zero for layer 0 (subsequent layers zeroed by node_fused)
    hipMemsetAsync(agg, 0, (size_t)N_NODES * 64 * 4, stream);

    for (int l = 0; l < 4; l++) {
        edge_fused_k<<<edge_grid, 256, 0, stream>>>(
            eidx, P, eW2p + (size_t)l * SE2, eb2 + (size_t)l * 64, agg, E);
        if (l < 3) {
            node_fused_k<0><<<gemm_grid, 512, 0, stream>>>(
                hbf, agg, nW1p + (size_t)l * SN1, nb1 + (size_t)l * 128,
                nW2p + (size_t)l * SN2, nb2 + (size_t)l * 128,
                W1p + (size_t)(l + 1) * SW1, biasP + (size_t)(l + 1) * 128,
                hFT, hbf, P, nullptr, agg, N_NODES);
        } else {
            node_fused_k<1><<<gemm_grid, 512, 0, stream>>>(
                hbf, agg, nW1p + (size_t)l * SN1, nb1 + (size_t)l * 128,
                nW2p + (size_t)l * SN2, nb2 + (size_t)l * 128,
                Woutp, b_out, hFT, hbf, nullptr, out, nullptr, N_NODES);
        }
    }
}